// Round 2
// baseline (426.073 us; speedup 1.0000x reference)
//
#include <hip/hip_runtime.h>
#include <hip/hip_bf16.h>

typedef __bf16 bf16x8 __attribute__((ext_vector_type(8)));
typedef float  f32x4  __attribute__((ext_vector_type(4)));

#define B_ 4
#define C_ 64
#define N_ 4096
#define O_ 16

__device__ __forceinline__ float wave_sum64(float v) {
#pragma unroll
  for (int off = 1; off < 64; off <<= 1) v += __shfl_xor(v, off);
  return v;
}

// ---------------------------------------------------------------------------
// Kernel 1: channel-attention Gram + max-subtract softmax.
// Block (b,c): att[b][c][d] = softmax_d( rowmax - G[c,d] ) = exp(rowmin-G)/sum
// ---------------------------------------------------------------------------
__global__ __launch_bounds__(256) void k1_gram_softmax(
    const float* __restrict__ x, float* __restrict__ att)
{
  __shared__ alignas(16) float xs[N_];
  __shared__ float grow[C_];
  const int b = blockIdx.x >> 6, c = blockIdx.x & 63;
  const float* xb = x + (size_t)b * C_ * N_;
  const float* xc = xb + (size_t)c * N_;
  const int t = threadIdx.x;
  for (int i = t; i < N_ / 4; i += 256)
    ((float4*)xs)[i] = ((const float4*)xc)[i];
  __syncthreads();
  const int w = __builtin_amdgcn_readfirstlane(t >> 6);
  const int lane = t & 63;
  for (int dd = 0; dd < 16; ++dd) {
    const int d = w * 16 + dd;
    const float* xd = xb + (size_t)d * N_;
    float s0 = 0.f, s1 = 0.f, s2 = 0.f, s3 = 0.f;
#pragma unroll
    for (int j = 0; j < 64; j += 4) {
      s0 += xs[lane + 64 * j]       * xd[lane + 64 * j];
      s1 += xs[lane + 64 * (j + 1)] * xd[lane + 64 * (j + 1)];
      s2 += xs[lane + 64 * (j + 2)] * xd[lane + 64 * (j + 2)];
      s3 += xs[lane + 64 * (j + 3)] * xd[lane + 64 * (j + 3)];
    }
    float s = wave_sum64((s0 + s1) + (s2 + s3));
    if (lane == 0) grow[d] = s;
  }
  __syncthreads();
  if (w == 0) {
    float gv = grow[lane];
    float mn = gv;
#pragma unroll
    for (int off = 1; off < 64; off <<= 1) mn = fminf(mn, __shfl_xor(mn, off));
    float p = expf(mn - gv);                 // softmax(rowmax - G) == exp(rowmin - G)/sum
    float ssum = wave_sum64(p);
    att[((size_t)(b * 64 + c) << 6) + lane] = p / ssum;
  }
}

// ---------------------------------------------------------------------------
// Kernel 2: fused per-pixel matvec with M = [att_c(64); wq(16); wk(16); wv(64)].
// Writes: d_out = gamma_ca*out_c + 2*x   (fp32, [b][c][n])
//         qT,kT  bf16 [b][n][16]  (MFMA-fragment friendly); q PRE-SCALED by
//         log2(e) so k3's softmax runs natively in the exp2 domain.
//         vB     bf16 [b][c][n]
// Wave-uniform row pointers -> scalar loads; x column in registers.
// ---------------------------------------------------------------------------
__global__ __launch_bounds__(256) void k2_proj(
    const float* __restrict__ x, const float* __restrict__ att,
    const float* __restrict__ wq, const float* __restrict__ bq,
    const float* __restrict__ wk, const float* __restrict__ bk,
    const float* __restrict__ wv, const float* __restrict__ bv,
    const float* __restrict__ gca,
    float* __restrict__ out, __bf16* __restrict__ qT,
    __bf16* __restrict__ kT, __bf16* __restrict__ vB)
{
  const int b = blockIdx.x >> 6;
  const int n0 = (blockIdx.x & 63) << 6;
  const int t = threadIdx.x;
  const int w = __builtin_amdgcn_readfirstlane(t >> 6);
  const int lane = t & 63;
  const int n = n0 + lane;
  const float* xb = x + ((size_t)b << 18);     // b*C*N
  float xr[64];
#pragma unroll
  for (int c = 0; c < 64; ++c) xr[c] = xb[((size_t)c << 12) + n];
  const float gamma = gca[0];
  for (int i = 0; i < 40; ++i) {
    const int r = w * 40 + i;                  // wave-uniform
    const float* mrow; float bias;
    if (r < 64)      { mrow = att + ((size_t)(b * 64 + r) << 6); bias = 0.f; }
    else if (r < 80) { mrow = wq + ((size_t)(r - 64) << 6); bias = bq[r - 64]; }
    else if (r < 96) { mrow = wk + ((size_t)(r - 80) << 6); bias = bk[r - 80]; }
    else             { mrow = wv + ((size_t)(r - 96) << 6); bias = bv[r - 96]; }
    float a0 = 0.f, a1 = 0.f, a2 = 0.f, a3 = 0.f;
#pragma unroll
    for (int c = 0; c < 64; c += 4) {
      a0 += mrow[c]     * xr[c];
      a1 += mrow[c + 1] * xr[c + 1];
      a2 += mrow[c + 2] * xr[c + 2];
      a3 += mrow[c + 3] * xr[c + 3];
    }
    const float acc = (a0 + a1) + (a2 + a3) + bias;
    if (r < 64) {
      out[((size_t)(b * 64 + r) << 12) + n] = gamma * acc + 2.f * xb[((size_t)r << 12) + n];
    } else if (r < 80) {
      // pre-scale q by log2(e): QK^T lands in exp2 domain (saves VALU in k3)
      qT[(((size_t)b << 12) + n) * 16 + (r - 64)] = (__bf16)(acc * 1.44269504f);
    } else if (r < 96) {
      kT[(((size_t)b << 12) + n) * 16 + (r - 80)] = (__bf16)acc;
    } else {
      vB[((size_t)(b * 64 + (r - 96)) << 12) + n] = (__bf16)acc;
    }
  }
}

// ---------------------------------------------------------------------------
// Kernel 3: flash spatial attention (bf16 MFMA), out += gamma_sa * softmax(QK^T) V
// Block = (b, 64 queries), 4 waves x 16 queries. KB = 64 keys per tile.
// S: mfma_f32_16x16x32_bf16, A=Q (o padded 16->32 with zeros), B=K from kT[n][16].
// PV: P transposed via per-wave private LDS, B=V from vB[c][n] tile.
// Double-buffered K/V LDS, register prefetch, ONE barrier per tile.
// Softmax runs in exp2 domain (q pre-scaled by log2 e in k2).
// ---------------------------------------------------------------------------
__global__ __launch_bounds__(256) void k3_attn(
    const __bf16* __restrict__ qT, const __bf16* __restrict__ kT,
    const __bf16* __restrict__ vB, const float* __restrict__ gsa,
    float* __restrict__ out)
{
  __shared__ alignas(16) __bf16 kbuf[2][64 * 24];   // [n][16o] pad->24
  __shared__ alignas(16) __bf16 vbuf[2][64 * 72];   // [c][64n] pad->72
  __shared__ alignas(16) __bf16 pbuf[4][16 * 72];   // per-wave [16q][64n] pad->72

  const int t = threadIdx.x;
  const int b = blockIdx.x >> 6;
  const int m0 = (blockIdx.x & 63) << 6;
  const int w = __builtin_amdgcn_readfirstlane(t >> 6);
  const int lane = t & 63;
  const int g = lane >> 4, qc = lane & 15;

  // Q A-fragment: row=qc, k(o) = 8g+j ; zero for g>=2 (o padded to 32)
  int4 qz = {0, 0, 0, 0};
  if (g < 2)
    qz = *(const int4*)(qT + (((size_t)b << 12) + m0 + (w << 4) + qc) * O_ + (g << 3));
  const bf16x8 qfrag = __builtin_bit_cast(bf16x8, qz);

  // staging addressing
  const int krow = t >> 1, khalf = t & 1;            // threads < 128
  const size_t kbase = (size_t)b * 65536 + (size_t)krow * 16 + 8 * khalf;
  const int kdst = krow * 24 + 8 * khalf;
  const int c0 = t >> 3, p0 = t & 7;
  const size_t vbase0 = ((size_t)(b * 64 + c0) << 12) + 8 * p0;
  const size_t vbase1 = ((size_t)(b * 64 + c0 + 32) << 12) + 8 * p0;
  const int vdst0 = c0 * 72 + 8 * p0;
  const int vdst1 = (c0 + 32) * 72 + 8 * p0;

  f32x4 acc[4];
#pragma unroll
  for (int i = 0; i < 4; ++i) acc[i] = f32x4{0.f, 0.f, 0.f, 0.f};
  float m_run[4] = {-1e30f, -1e30f, -1e30f, -1e30f};
  float l_run[4] = {0.f, 0.f, 0.f, 0.f};

  // prologue: stage tile 0
  int4 kreg = {0, 0, 0, 0}, vreg0, vreg1;
  if (t < 128) kreg = *(const int4*)(kT + kbase);
  vreg0 = *(const int4*)(vB + vbase0);
  vreg1 = *(const int4*)(vB + vbase1);
  if (t < 128) *(int4*)&kbuf[0][kdst] = kreg;
  *(int4*)&vbuf[0][vdst0] = vreg0;
  *(int4*)&vbuf[0][vdst1] = vreg1;

  const f32x4 zero4 = {0.f, 0.f, 0.f, 0.f};
  for (int it = 0; it < 64; ++it) {
    const int cur = it & 1;
    if (it < 63) {  // prefetch next tile into registers (latency hides under compute)
      if (t < 128) kreg = *(const int4*)(kT + kbase + (size_t)(it + 1) * 1024);
      vreg0 = *(const int4*)(vB + vbase0 + (size_t)(it + 1) * 64);
      vreg1 = *(const int4*)(vB + vbase1 + (size_t)(it + 1) * 64);
    }
    __syncthreads();

    // ---- S = Q K^T  (16q x 64n per wave), exp2 domain ----
    f32x4 sv[4];
#pragma unroll
    for (int nt = 0; nt < 4; ++nt) {
      const bf16x8 kb = *(const bf16x8*)&kbuf[cur][(nt * 16 + qc) * 24 + 8 * (g & 1)];
      sv[nt] = __builtin_amdgcn_mfma_f32_16x16x32_bf16(qfrag, kb, zero4, 0, 0, 0);
    }

    // ---- online softmax; rows q = 4g + r, cols spread over qc-lanes ----
    float mnew[4], scv[4];
#pragma unroll
    for (int r = 0; r < 4; ++r) {
      float tm = fmaxf(fmaxf(sv[0][r], sv[1][r]), fmaxf(sv[2][r], sv[3][r]));
#pragma unroll
      for (int off = 1; off < 16; off <<= 1) tm = fmaxf(tm, __shfl_xor(tm, off));
      mnew[r] = fmaxf(m_run[r], tm);
      scv[r] = exp2f(m_run[r] - mnew[r]);
    }
    float p[4][4];
#pragma unroll
    for (int nt = 0; nt < 4; ++nt)
#pragma unroll
      for (int r = 0; r < 4; ++r)
        p[nt][r] = exp2f(sv[nt][r] - mnew[r]);
#pragma unroll
    for (int r = 0; r < 4; ++r) {
      float ts = (p[0][r] + p[1][r]) + (p[2][r] + p[3][r]);
#pragma unroll
      for (int off = 1; off < 16; off <<= 1) ts += __shfl_xor(ts, off);
      l_run[r] = l_run[r] * scv[r] + ts;
      m_run[r] = mnew[r];
    }
#pragma unroll
    for (int ct = 0; ct < 4; ++ct) {
      acc[ct][0] *= scv[0]; acc[ct][1] *= scv[1];
      acc[ct][2] *= scv[2]; acc[ct][3] *= scv[3];
    }

    // ---- P -> bf16 into per-wave LDS (transpose for A-fragment) ----
    __bf16* pw = &pbuf[w][0];
#pragma unroll
    for (int nt = 0; nt < 4; ++nt)
#pragma unroll
      for (int r = 0; r < 4; ++r)
        pw[(4 * g + r) * 72 + nt * 16 + qc] = (__bf16)p[nt][r];

    // ---- PV: acc[ct] += P(16q x 64n) * V(64n x 16c per tile) ----
#pragma unroll
    for (int s2 = 0; s2 < 2; ++s2) {
      const bf16x8 af = *(const bf16x8*)&pw[qc * 72 + 32 * s2 + 8 * g];
#pragma unroll
      for (int ct = 0; ct < 4; ++ct) {
        const bf16x8 bv = *(const bf16x8*)&vbuf[cur][(ct * 16 + qc) * 72 + 32 * s2 + 8 * g];
        acc[ct] = __builtin_amdgcn_mfma_f32_16x16x32_bf16(af, bv, acc[ct], 0, 0, 0);
      }
    }

    // stage next tile into the other buffer (no barrier needed here:
    // buf[cur^1] was last READ before the barrier at the top of this iter)
    if (it < 63) {
      if (t < 128) *(int4*)&kbuf[cur ^ 1][kdst] = kreg;
      *(int4*)&vbuf[cur ^ 1][vdst0] = vreg0;
      *(int4*)&vbuf[cur ^ 1][vdst1] = vreg1;
    }
  }

  // ---- epilogue: out += gamma_sa * acc / l ----
  const float gamma = gsa[0];
#pragma unroll
  for (int ct = 0; ct < 4; ++ct) {
    const int c = ct * 16 + qc;
    float* op = out + ((size_t)(b * 64 + c) << 12) + m0 + (w << 4) + 4 * g;
#pragma unroll
    for (int r = 0; r < 4; ++r)
      op[r] += gamma * (acc[ct][r] / l_run[r]);
  }
}

// ---------------------------------------------------------------------------
extern "C" void kernel_launch(void* const* d_in, const int* in_sizes, int n_in,
                              void* d_out, int out_size, void* d_ws, size_t ws_size,
                              hipStream_t stream)
{
  const float* x   = (const float*)d_in[0];
  const float* wq  = (const float*)d_in[1];
  const float* bq  = (const float*)d_in[2];
  const float* wk  = (const float*)d_in[3];
  const float* bk  = (const float*)d_in[4];
  const float* wv  = (const float*)d_in[5];
  const float* bv  = (const float*)d_in[6];
  const float* gca = (const float*)d_in[7];
  const float* gsa = (const float*)d_in[8];
  float* out = (float*)d_out;

  char* ws = (char*)d_ws;
  float*  att = (float*)ws;                          // 4*64*64*4   = 65536 B
  __bf16* qT  = (__bf16*)(ws + 65536);               // 4*4096*16*2 = 524288 B
  __bf16* kT  = (__bf16*)(ws + 65536 + 524288);      // 524288 B
  __bf16* vB  = (__bf16*)(ws + 65536 + 2 * 524288);  // 4*64*4096*2 = 2097152 B

  hipLaunchKernelGGL(k1_gram_softmax, dim3(256), dim3(256), 0, stream, x, att);
  hipLaunchKernelGGL(k2_proj, dim3(256), dim3(256), 0, stream,
                     x, att, wq, bq, wk, bk, wv, bv, gca, out, qT, kT, vB);
  hipLaunchKernelGGL(k3_attn, dim3(256), dim3(256), 0, stream, qT, kT, vB, gsa, out);
}

// Round 4
// 332.582 us; speedup vs baseline: 1.2811x; 1.2811x over previous
//
#include <hip/hip_runtime.h>
#include <hip/hip_bf16.h>

typedef __bf16 bf16x8 __attribute__((ext_vector_type(8)));
typedef float  f32x4  __attribute__((ext_vector_type(4)));

#define B_ 4
#define C_ 64
#define N_ 4096
#define O_ 16

__device__ __forceinline__ float wave_sum64(float v) {
#pragma unroll
  for (int off = 1; off < 64; off <<= 1) v += __shfl_xor(v, off);
  return v;
}

// ---------------------------------------------------------------------------
// Kernel 0: zero the Gram accumulator (graph-capture-safe replacement for
// hipMemsetAsync). 16 blocks x 256 threads x 1 float4 = 65536 B.
// ---------------------------------------------------------------------------
__global__ __launch_bounds__(256) void k0_zero(float4* __restrict__ G4)
{
  G4[blockIdx.x * 256 + threadIdx.x] = float4{0.f, 0.f, 0.f, 0.f};
}

// ---------------------------------------------------------------------------
// Kernel 1: Gram partial sums via LDS-tiled outer products.
// Grid: 4b x 32 chunks (128 cols). Block stages X[b][:,chunk] TRANSPOSED in
// LDS (pad 68 keeps b128 alignment; XOR row-swizzle fixes staging-write
// conflicts). Each thread owns a 4x4 tile of G[b], accumulates over 128 cols,
// then atomicAdd (G pre-zeroed by k0_zero).
// ---------------------------------------------------------------------------
__global__ __launch_bounds__(256) void k1_gram(
    const float* __restrict__ x, float* __restrict__ G)
{
  __shared__ alignas(16) float xsT[128 * 68];   // [col][row^swz], 34.8 KB
  const int b = blockIdx.x >> 5;
  const int n0 = (blockIdx.x & 31) << 7;
  const float* xb = x + ((size_t)b << 18);
  const int t = threadIdx.x;

  // stage: 64 rows x 128 cols, coalesced float4 reads (512B per 32 lanes/row)
#pragma unroll
  for (int j = 0; j < 8; ++j) {
    const int idx = t + 256 * j;
    const int row = idx >> 5;
    const int c4 = idx & 31;
    const float4 v = *(const float4*)(xb + (size_t)row * N_ + n0 + c4 * 4);
    const int sw = (c4 & 7) << 2;              // row-XOR swizzle (2-way banks)
    xsT[(4 * c4 + 0) * 68 + (row ^ sw)] = v.x;
    xsT[(4 * c4 + 1) * 68 + (row ^ sw)] = v.y;
    xsT[(4 * c4 + 2) * 68 + (row ^ sw)] = v.z;
    xsT[(4 * c4 + 3) * 68 + (row ^ sw)] = v.w;
  }
  __syncthreads();

  const int c0 = (t >> 4) << 2;   // 0,4,...,60
  const int d0 = (t & 15) << 2;   // 0,4,...,60
  f32x4 a0 = {0, 0, 0, 0}, a1 = {0, 0, 0, 0}, a2 = {0, 0, 0, 0}, a3 = {0, 0, 0, 0};
#pragma unroll 4
  for (int i = 0; i < 128; ++i) {
    const int sw = ((i >> 2) & 7) << 2;
    const f32x4 xc = *(const f32x4*)&xsT[i * 68 + (c0 ^ sw)];
    const f32x4 xd = *(const f32x4*)&xsT[i * 68 + (d0 ^ sw)];
    a0 += xc[0] * xd; a1 += xc[1] * xd; a2 += xc[2] * xd; a3 += xc[3] * xd;
  }
  float* Gb = G + (b << 12);
#pragma unroll
  for (int k = 0; k < 4; ++k) {
    atomicAdd(&Gb[(c0 + 0) * 64 + d0 + k], a0[k]);
    atomicAdd(&Gb[(c0 + 1) * 64 + d0 + k], a1[k]);
    atomicAdd(&Gb[(c0 + 2) * 64 + d0 + k], a2[k]);
    atomicAdd(&Gb[(c0 + 3) * 64 + d0 + k], a3[k]);
  }
}

// ---------------------------------------------------------------------------
// Kernel 1b: per-row softmax of (rowmax - G) == exp(rowmin - G)/sum.
// Grid 64 blocks x 256: one wave per (b,c) row, lane = d.
// ---------------------------------------------------------------------------
__global__ __launch_bounds__(256) void k1b_softmax(
    const float* __restrict__ G, float* __restrict__ att)
{
  const int t = threadIdx.x;
  const int row = blockIdx.x * 4 + (t >> 6);   // 0..255 = (b*64+c)
  const int lane = t & 63;
  const float gv = G[(size_t)row * 64 + lane];
  float mn = gv;
#pragma unroll
  for (int off = 1; off < 64; off <<= 1) mn = fminf(mn, __shfl_xor(mn, off));
  const float p = expf(mn - gv);
  const float s = wave_sum64(p);
  att[(size_t)row * 64 + lane] = p / s;
}

// ---------------------------------------------------------------------------
// Kernel 2: fused per-pixel matvec with M = [att_c(64); wq(16); wk(16); wv(64)].
// Writes: d_out = gamma_ca*out_c + 2*x   (fp32, [b][c][n])
//         qT,kT  bf16 [b][n][16] (q pre-scaled by log2 e), vB bf16 [b][c][n]
// Grid 512: (b, chunk of 64 px, half). Each wave 20 wave-uniform rows.
// ---------------------------------------------------------------------------
__global__ __launch_bounds__(256) void k2_proj(
    const float* __restrict__ x, const float* __restrict__ att,
    const float* __restrict__ wq, const float* __restrict__ bq,
    const float* __restrict__ wk, const float* __restrict__ bk,
    const float* __restrict__ wv, const float* __restrict__ bv,
    const float* __restrict__ gca,
    float* __restrict__ out, __bf16* __restrict__ qT,
    __bf16* __restrict__ kT, __bf16* __restrict__ vB)
{
  const int bid = blockIdx.x;
  const int b = bid >> 7;
  const int n0 = ((bid >> 1) & 63) << 6;
  const int h = bid & 1;
  const int t = threadIdx.x;
  const int w = __builtin_amdgcn_readfirstlane(t >> 6);
  const int lane = t & 63;
  const int n = n0 + lane;
  const float* xb = x + ((size_t)b << 18);
  float xr[64];
#pragma unroll
  for (int c = 0; c < 64; ++c) xr[c] = xb[((size_t)c << 12) + n];
  const float gamma = gca[0];
  for (int i = 0; i < 20; ++i) {
    const int r = h * 80 + w * 20 + i;         // wave-uniform
    const float* mrow; float bias;
    if (r < 64)      { mrow = att + ((size_t)(b * 64 + r) << 6); bias = 0.f; }
    else if (r < 80) { mrow = wq + ((size_t)(r - 64) << 6); bias = bq[r - 64]; }
    else if (r < 96) { mrow = wk + ((size_t)(r - 80) << 6); bias = bk[r - 80]; }
    else             { mrow = wv + ((size_t)(r - 96) << 6); bias = bv[r - 96]; }
    float a0 = 0.f, a1 = 0.f, a2 = 0.f, a3 = 0.f;
#pragma unroll
    for (int c = 0; c < 64; c += 4) {
      a0 += mrow[c]     * xr[c];
      a1 += mrow[c + 1] * xr[c + 1];
      a2 += mrow[c + 2] * xr[c + 2];
      a3 += mrow[c + 3] * xr[c + 3];
    }
    const float acc = (a0 + a1) + (a2 + a3) + bias;
    if (r < 64) {
      out[((size_t)(b * 64 + r) << 12) + n] = gamma * acc + 2.f * xb[((size_t)r << 12) + n];
    } else if (r < 80) {
      // pre-scale q by log2(e): QK^T lands in exp2 domain (saves VALU in k3)
      qT[(((size_t)b << 12) + n) * 16 + (r - 64)] = (__bf16)(acc * 1.44269504f);
    } else if (r < 96) {
      kT[(((size_t)b << 12) + n) * 16 + (r - 80)] = (__bf16)acc;
    } else {
      vB[((size_t)(b * 64 + (r - 96)) << 12) + n] = (__bf16)acc;
    }
  }
}

// ---------------------------------------------------------------------------
// Kernel 3: flash spatial attention (bf16 MFMA), out += gamma_sa * softmax(QK^T) V
// Block = (b, 32 queries), 2 waves x 16 queries, 128 threads. Grid 512 ->
// 2 blocks/CU with INDEPENDENT barrier domains (overlap one block's softmax
// chain with the other's MFMA/LDS). KB = 64 keys per tile.
// Double-buffered K/V LDS, register prefetch, ONE barrier per tile.
// Softmax runs in exp2 domain (q pre-scaled by log2 e in k2).
// ---------------------------------------------------------------------------
__global__ __launch_bounds__(128) void k3_attn(
    const __bf16* __restrict__ qT, const __bf16* __restrict__ kT,
    const __bf16* __restrict__ vB, const float* __restrict__ gsa,
    float* __restrict__ out)
{
  __shared__ alignas(16) __bf16 kbuf[2][64 * 24];   // [n][16o] pad->24
  __shared__ alignas(16) __bf16 vbuf[2][64 * 72];   // [c][64n] pad->72
  __shared__ alignas(16) __bf16 pbuf[2][16 * 72];   // per-wave [16q][64n] pad->72

  const int t = threadIdx.x;                  // 0..127
  const int b = blockIdx.x >> 7;
  const int m0 = (blockIdx.x & 127) << 5;     // 32-query tile
  const int w = __builtin_amdgcn_readfirstlane(t >> 6);   // 0..1
  const int lane = t & 63;
  const int g = lane >> 4, qc = lane & 15;

  // Q A-fragment: row=qc, k(o) = 8g+j ; zero for g>=2 (o padded to 32)
  int4 qz = {0, 0, 0, 0};
  if (g < 2)
    qz = *(const int4*)(qT + (((size_t)b << 12) + m0 + (w << 4) + qc) * O_ + (g << 3));
  const bf16x8 qfrag = __builtin_bit_cast(bf16x8, qz);

  // staging addressing: K tile = 128 int4 (1/thread), V tile = 512 int4 (4/thread)
  const int krow = t >> 1, khalf = t & 1;
  const size_t kbase = (size_t)b * 65536 + (size_t)krow * 16 + 8 * khalf;
  const int kdst = krow * 24 + 8 * khalf;
  size_t vbase[4]; int vdst[4];
#pragma unroll
  for (int j = 0; j < 4; ++j) {
    const int idx = t + 128 * j;
    const int c = idx >> 3, p0 = idx & 7;
    vbase[j] = ((size_t)(b * 64 + c) << 12) + 8 * p0;
    vdst[j] = c * 72 + 8 * p0;
  }

  f32x4 acc[4];
#pragma unroll
  for (int i = 0; i < 4; ++i) acc[i] = f32x4{0.f, 0.f, 0.f, 0.f};
  float m_run[4] = {-1e30f, -1e30f, -1e30f, -1e30f};
  float l_run[4] = {0.f, 0.f, 0.f, 0.f};

  // prologue: stage tile 0
  int4 kreg, vreg[4];
  kreg = *(const int4*)(kT + kbase);
#pragma unroll
  for (int j = 0; j < 4; ++j) vreg[j] = *(const int4*)(vB + vbase[j]);
  *(int4*)&kbuf[0][kdst] = kreg;
#pragma unroll
  for (int j = 0; j < 4; ++j) *(int4*)&vbuf[0][vdst[j]] = vreg[j];

  const f32x4 zero4 = {0.f, 0.f, 0.f, 0.f};
  for (int it = 0; it < 64; ++it) {
    const int cur = it & 1;
    if (it < 63) {  // prefetch next tile into registers (latency hides under compute)
      kreg = *(const int4*)(kT + kbase + (size_t)(it + 1) * 1024);
#pragma unroll
      for (int j = 0; j < 4; ++j)
        vreg[j] = *(const int4*)(vB + vbase[j] + (size_t)(it + 1) * 64);
    }
    __syncthreads();

    // ---- S = Q K^T  (16q x 64n per wave), exp2 domain ----
    f32x4 sv[4];
#pragma unroll
    for (int nt = 0; nt < 4; ++nt) {
      const bf16x8 kb = *(const bf16x8*)&kbuf[cur][(nt * 16 + qc) * 24 + 8 * (g & 1)];
      sv[nt] = __builtin_amdgcn_mfma_f32_16x16x32_bf16(qfrag, kb, zero4, 0, 0, 0);
    }

    // ---- online softmax; rows q = 4g + r, cols spread over qc-lanes ----
    float mnew[4], scv[4];
#pragma unroll
    for (int r = 0; r < 4; ++r) {
      float tm = fmaxf(fmaxf(sv[0][r], sv[1][r]), fmaxf(sv[2][r], sv[3][r]));
#pragma unroll
      for (int off = 1; off < 16; off <<= 1) tm = fmaxf(tm, __shfl_xor(tm, off));
      mnew[r] = fmaxf(m_run[r], tm);
      scv[r] = exp2f(m_run[r] - mnew[r]);
    }
    float p[4][4];
#pragma unroll
    for (int nt = 0; nt < 4; ++nt)
#pragma unroll
      for (int r = 0; r < 4; ++r)
        p[nt][r] = exp2f(sv[nt][r] - mnew[r]);
#pragma unroll
    for (int r = 0; r < 4; ++r) {
      float ts = (p[0][r] + p[1][r]) + (p[2][r] + p[3][r]);
#pragma unroll
      for (int off = 1; off < 16; off <<= 1) ts += __shfl_xor(ts, off);
      l_run[r] = l_run[r] * scv[r] + ts;
      m_run[r] = mnew[r];
    }
#pragma unroll
    for (int ct = 0; ct < 4; ++ct) {
      acc[ct][0] *= scv[0]; acc[ct][1] *= scv[1];
      acc[ct][2] *= scv[2]; acc[ct][3] *= scv[3];
    }

    // ---- P -> bf16 into per-wave LDS (transpose for A-fragment) ----
    __bf16* pw = &pbuf[w][0];
#pragma unroll
    for (int nt = 0; nt < 4; ++nt)
#pragma unroll
      for (int r = 0; r < 4; ++r)
        pw[(4 * g + r) * 72 + nt * 16 + qc] = (__bf16)p[nt][r];

    // ---- PV: acc[ct] += P(16q x 64n) * V(64n x 16c per tile) ----
#pragma unroll
    for (int s2 = 0; s2 < 2; ++s2) {
      const bf16x8 af = *(const bf16x8*)&pw[qc * 72 + 32 * s2 + 8 * g];
#pragma unroll
      for (int ct = 0; ct < 4; ++ct) {
        const bf16x8 bv = *(const bf16x8*)&vbuf[cur][(ct * 16 + qc) * 72 + 32 * s2 + 8 * g];
        acc[ct] = __builtin_amdgcn_mfma_f32_16x16x32_bf16(af, bv, acc[ct], 0, 0, 0);
      }
    }

    // stage next tile into the other buffer (no barrier needed here:
    // buf[cur^1] was last READ before the barrier at the top of this iter)
    if (it < 63) {
      *(int4*)&kbuf[cur ^ 1][kdst] = kreg;
#pragma unroll
      for (int j = 0; j < 4; ++j) *(int4*)&vbuf[cur ^ 1][vdst[j]] = vreg[j];
    }
  }

  // ---- epilogue: out += gamma_sa * acc / l ----
  const float gamma = gsa[0];
#pragma unroll
  for (int ct = 0; ct < 4; ++ct) {
    const int c = ct * 16 + qc;
    float* op = out + ((size_t)(b * 64 + c) << 12) + m0 + (w << 4) + 4 * g;
#pragma unroll
    for (int r = 0; r < 4; ++r)
      op[r] += gamma * (acc[ct][r] / l_run[r]);
  }
}

// ---------------------------------------------------------------------------
extern "C" void kernel_launch(void* const* d_in, const int* in_sizes, int n_in,
                              void* d_out, int out_size, void* d_ws, size_t ws_size,
                              hipStream_t stream)
{
  const float* x   = (const float*)d_in[0];
  const float* wq  = (const float*)d_in[1];
  const float* bq  = (const float*)d_in[2];
  const float* wk  = (const float*)d_in[3];
  const float* bk  = (const float*)d_in[4];
  const float* wv  = (const float*)d_in[5];
  const float* bv  = (const float*)d_in[6];
  const float* gca = (const float*)d_in[7];
  const float* gsa = (const float*)d_in[8];
  float* out = (float*)d_out;

  char* ws = (char*)d_ws;
  float*  G   = (float*)ws;                           // 4*64*64*4   = 65536 B
  float*  att = (float*)(ws + 65536);                 // 65536 B
  __bf16* qT  = (__bf16*)(ws + 131072);               // 4*4096*16*2 = 524288 B
  __bf16* kT  = (__bf16*)(ws + 131072 + 524288);      // 524288 B
  __bf16* vB  = (__bf16*)(ws + 131072 + 2 * 524288);  // 4*64*4096*2 = 2097152 B

  hipLaunchKernelGGL(k0_zero, dim3(16), dim3(256), 0, stream, (float4*)G);
  hipLaunchKernelGGL(k1_gram, dim3(128), dim3(256), 0, stream, x, G);
  hipLaunchKernelGGL(k1b_softmax, dim3(64), dim3(256), 0, stream, G, att);
  hipLaunchKernelGGL(k2_proj, dim3(512), dim3(256), 0, stream,
                     x, att, wq, bq, wk, bk, wv, bv, gca, out, qT, kT, vB);
  hipLaunchKernelGGL(k3_attn, dim3(512), dim3(128), 0, stream, qT, kT, vB, gsa, out);
}

// Round 10
// 174.848 us; speedup vs baseline: 2.4368x; 1.9021x over previous
//
#include <hip/hip_runtime.h>
#include <hip/hip_bf16.h>

typedef __bf16 bf16x8 __attribute__((ext_vector_type(8)));
typedef float  f32x4  __attribute__((ext_vector_type(4)));

#define B_ 4
#define C_ 64
#define N_ 4096
#define O_ 16

__device__ __forceinline__ float wave_sum64(float v) {
#pragma unroll
  for (int off = 1; off < 64; off <<= 1) v += __shfl_xor(v, off);
  return v;
}

// ---------------------------------------------------------------------------
// Kernel 1: Gram partials via LDS-tiled outer products. NO atomics: each
// block (b, chunk of 128 cols) writes its own 64x64 fp32 partial to Gp[blk].
// ---------------------------------------------------------------------------
__global__ __launch_bounds__(256) void k1_gram(
    const float* __restrict__ x, float* __restrict__ Gp)
{
  __shared__ alignas(16) float xsT[128 * 68];   // [col][row^swz], 34.8 KB
  const int b = blockIdx.x >> 5;
  const int n0 = (blockIdx.x & 31) << 7;
  const float* xb = x + ((size_t)b << 18);
  const int t = threadIdx.x;

#pragma unroll
  for (int j = 0; j < 8; ++j) {
    const int idx = t + 256 * j;
    const int row = idx >> 5;
    const int c4 = idx & 31;
    const float4 v = *(const float4*)(xb + (size_t)row * N_ + n0 + c4 * 4);
    const int sw = (c4 & 7) << 2;              // row-XOR swizzle (2-way banks)
    xsT[(4 * c4 + 0) * 68 + (row ^ sw)] = v.x;
    xsT[(4 * c4 + 1) * 68 + (row ^ sw)] = v.y;
    xsT[(4 * c4 + 2) * 68 + (row ^ sw)] = v.z;
    xsT[(4 * c4 + 3) * 68 + (row ^ sw)] = v.w;
  }
  __syncthreads();

  const int c0 = (t >> 4) << 2;   // 0,4,...,60
  const int d0 = (t & 15) << 2;   // 0,4,...,60
  f32x4 a0 = {0, 0, 0, 0}, a1 = {0, 0, 0, 0}, a2 = {0, 0, 0, 0}, a3 = {0, 0, 0, 0};
#pragma unroll 4
  for (int i = 0; i < 128; ++i) {
    const int sw = ((i >> 2) & 7) << 2;
    const f32x4 xc = *(const f32x4*)&xsT[i * 68 + (c0 ^ sw)];
    const f32x4 xd = *(const f32x4*)&xsT[i * 68 + (d0 ^ sw)];
    a0 += xc[0] * xd; a1 += xc[1] * xd; a2 += xc[2] * xd; a3 += xc[3] * xd;
  }
  // coalesced partial store: thread t owns rows c0..c0+3, cols d0..d0+3
  float* Gb = Gp + ((size_t)blockIdx.x << 12);
  *(f32x4*)&Gb[(c0 + 0) * 64 + d0] = a0;
  *(f32x4*)&Gb[(c0 + 1) * 64 + d0] = a1;
  *(f32x4*)&Gb[(c0 + 2) * 64 + d0] = a2;
  *(f32x4*)&Gb[(c0 + 3) * 64 + d0] = a3;
}

// ---------------------------------------------------------------------------
// Kernel 1b: sum 32 chunk-partials per row, then softmax of (rowmax - G)
// == exp(rowmin - G)/sum. Grid 64 x 256: one wave per (b,c) row, lane = d.
// ---------------------------------------------------------------------------
__global__ __launch_bounds__(256) void k1b_softmax(
    const float* __restrict__ Gp, float* __restrict__ att)
{
  const int t = threadIdx.x;
  const int row = blockIdx.x * 4 + (t >> 6);   // 0..255 = (b*64+c)
  const int lane = t & 63;
  const int b = row >> 6, c = row & 63;
  const size_t base = (((size_t)b * 32) << 12) + (c << 6) + lane;
  float gv = 0.f;
#pragma unroll
  for (int ch = 0; ch < 32; ++ch) gv += Gp[base + ((size_t)ch << 12)];
  float mn = gv;
#pragma unroll
  for (int off = 1; off < 64; off <<= 1) mn = fminf(mn, __shfl_xor(mn, off));
  const float p = expf(mn - gv);
  const float s = wave_sum64(p);
  att[(size_t)row * 64 + lane] = p / s;
}

// ---------------------------------------------------------------------------
// Kernel 2: fused per-pixel matvec, M = [att_c(64); wq(16); wk(16); wv(64)].
// (validated r4)
// ---------------------------------------------------------------------------
__global__ __launch_bounds__(256) void k2_proj(
    const float* __restrict__ x, const float* __restrict__ att,
    const float* __restrict__ wq, const float* __restrict__ bq,
    const float* __restrict__ wk, const float* __restrict__ bk,
    const float* __restrict__ wv, const float* __restrict__ bv,
    const float* __restrict__ gca,
    float* __restrict__ out, __bf16* __restrict__ qT,
    __bf16* __restrict__ kT, __bf16* __restrict__ vB)
{
  const int bid = blockIdx.x;
  const int b = bid >> 7;
  const int n0 = ((bid >> 1) & 63) << 6;
  const int h = bid & 1;
  const int t = threadIdx.x;
  const int w = __builtin_amdgcn_readfirstlane(t >> 6);
  const int lane = t & 63;
  const int n = n0 + lane;
  const float* xb = x + ((size_t)b << 18);
  float xr[64];
#pragma unroll
  for (int c = 0; c < 64; ++c) xr[c] = xb[((size_t)c << 12) + n];
  const float gamma = gca[0];
  for (int i = 0; i < 20; ++i) {
    const int r = h * 80 + w * 20 + i;         // wave-uniform
    const float* mrow; float bias;
    if (r < 64)      { mrow = att + ((size_t)(b * 64 + r) << 6); bias = 0.f; }
    else if (r < 80) { mrow = wq + ((size_t)(r - 64) << 6); bias = bq[r - 64]; }
    else if (r < 96) { mrow = wk + ((size_t)(r - 80) << 6); bias = bk[r - 80]; }
    else             { mrow = wv + ((size_t)(r - 96) << 6); bias = bv[r - 96]; }
    float a0 = 0.f, a1 = 0.f, a2 = 0.f, a3 = 0.f;
#pragma unroll
    for (int c = 0; c < 64; c += 4) {
      a0 += mrow[c]     * xr[c];
      a1 += mrow[c + 1] * xr[c + 1];
      a2 += mrow[c + 2] * xr[c + 2];
      a3 += mrow[c + 3] * xr[c + 3];
    }
    const float acc = (a0 + a1) + (a2 + a3) + bias;
    if (r < 64) {
      out[((size_t)(b * 64 + r) << 12) + n] = gamma * acc + 2.f * xb[((size_t)r << 12) + n];
    } else if (r < 80) {
      // pre-scale q by log2(e): QK^T lands in exp2 domain
      qT[(((size_t)b << 12) + n) * 16 + (r - 64)] = (__bf16)(acc * 1.44269504f);
    } else if (r < 96) {
      kT[(((size_t)b << 12) + n) * 16 + (r - 80)] = (__bf16)acc;
    } else {
      vB[((size_t)(b * 64 + (r - 96)) << 12) + n] = (__bf16)acc;
    }
  }
}

// ---------------------------------------------------------------------------
// Kernel 3: flash spatial attention, templated KV-split.
// NSPLIT=4: grid 1024 = (b, qt, s); 4 blocks/CU; fp32 partials + k3b merge.
// NSPLIT=1: grid 256 = (b, qt); direct finalize into out (r2-style fallback,
//           used when ws_size can't hold the partials).
// Block = 256 thr = 4 waves x 16 queries; keys [s*N/NSPLIT ...), tiles of 64.
// T14 order: barrier -> issue next-tile global loads -> compute -> LDS write.
// Compute core (QK^T/softmax/P-transpose/PV) identical to validated r4.
// ---------------------------------------------------------------------------
template <int NSPLIT>
__global__ __launch_bounds__(256) void k3_attn(
    const __bf16* __restrict__ qT, const __bf16* __restrict__ kT,
    const __bf16* __restrict__ vB, const float* __restrict__ gsa,
    float* __restrict__ out,
    float* __restrict__ accP, float* __restrict__ mP, float* __restrict__ lP)
{
  constexpr int NITER = 64 / NSPLIT;
  __shared__ alignas(16) __bf16 kbuf[2][64 * 24];   // [n][16o] pad->24, 6 KB
  __shared__ alignas(16) __bf16 vbuf[2][64 * 72];   // [c][64n] pad->72, 18 KB
  __shared__ alignas(16) __bf16 pbuf[4][16 * 72];   // per-wave [16q][64n], 9 KB

  const int t = threadIdx.x;                  // 0..255
  const int blk = blockIdx.x;
  const int s = blk % NSPLIT;
  const int qt = (blk / NSPLIT) & 63;
  const int b = blk / (NSPLIT * 64);
  const int m0 = qt << 6;
  const int tix0 = s * NITER;                 // first 64-key tile of this split
  const int w = __builtin_amdgcn_readfirstlane(t >> 6);   // 0..3
  const int lane = t & 63;
  const int g = lane >> 4, qc = lane & 15;

  // Q A-fragment: row=qc, k(o)=8g+j; zero for g>=2 (o padded 16->32)
  int4 qz = {0, 0, 0, 0};
  if (g < 2)
    qz = *(const int4*)(qT + (((size_t)b << 12) + m0 + (w << 4) + qc) * O_ + (g << 3));
  const bf16x8 qfrag = __builtin_bit_cast(bf16x8, qz);

  // staging addressing: K tile = 128 int4 (threads<128), V tile = 512 int4 (2/thr)
  const int krow = t >> 1, khalf = t & 1;
  const size_t kbase = (size_t)b * 65536 + (size_t)tix0 * 1024 + (size_t)krow * 16 + 8 * khalf;
  const int kdst = krow * 24 + 8 * khalf;
  size_t vbase[2]; int vdst[2];
#pragma unroll
  for (int j = 0; j < 2; ++j) {
    const int idx = t + 256 * j;
    const int c = idx >> 3, p0 = idx & 7;
    vbase[j] = ((size_t)(b * 64 + c) << 12) + (size_t)tix0 * 64 + 8 * p0;
    vdst[j] = c * 72 + 8 * p0;
  }

  f32x4 acc[4];
#pragma unroll
  for (int i = 0; i < 4; ++i) acc[i] = f32x4{0.f, 0.f, 0.f, 0.f};
  float m_run[4] = {-1e30f, -1e30f, -1e30f, -1e30f};
  float l_run[4] = {0.f, 0.f, 0.f, 0.f};

  // prologue: stage tile 0 of this split
  int4 kreg = {0, 0, 0, 0}, vreg0, vreg1;
  if (t < 128) kreg = *(const int4*)(kT + kbase);
  vreg0 = *(const int4*)(vB + vbase[0]);
  vreg1 = *(const int4*)(vB + vbase[1]);
  if (t < 128) *(int4*)&kbuf[0][kdst] = kreg;
  *(int4*)&vbuf[0][vdst[0]] = vreg0;
  *(int4*)&vbuf[0][vdst[1]] = vreg1;

  const f32x4 zero4 = {0.f, 0.f, 0.f, 0.f};
  for (int it = 0; it < NITER; ++it) {
    const int cur = it & 1;
    __syncthreads();   // buf[cur] ready (written at end of prev iter)

    // T14: issue next-tile global loads NOW; vmcnt drains only at iter end
    if (it < NITER - 1) {
      if (t < 128) kreg = *(const int4*)(kT + kbase + (size_t)(it + 1) * 1024);
      vreg0 = *(const int4*)(vB + vbase[0] + (size_t)(it + 1) * 64);
      vreg1 = *(const int4*)(vB + vbase[1] + (size_t)(it + 1) * 64);
    }

    // ---- S = Q K^T  (16q x 64n per wave), exp2 domain ----
    f32x4 sv[4];
#pragma unroll
    for (int nt = 0; nt < 4; ++nt) {
      const bf16x8 kb = *(const bf16x8*)&kbuf[cur][(nt * 16 + qc) * 24 + 8 * (g & 1)];
      sv[nt] = __builtin_amdgcn_mfma_f32_16x16x32_bf16(qfrag, kb, zero4, 0, 0, 0);
    }

    // ---- online softmax; rows q = 4g + r, cols spread over qc-lanes ----
    float mnew[4], scv[4];
#pragma unroll
    for (int r = 0; r < 4; ++r) {
      float tm = fmaxf(fmaxf(sv[0][r], sv[1][r]), fmaxf(sv[2][r], sv[3][r]));
#pragma unroll
      for (int off = 1; off < 16; off <<= 1) tm = fmaxf(tm, __shfl_xor(tm, off));
      mnew[r] = fmaxf(m_run[r], tm);
      scv[r] = exp2f(m_run[r] - mnew[r]);
    }
    float p[4][4];
#pragma unroll
    for (int nt = 0; nt < 4; ++nt)
#pragma unroll
      for (int r = 0; r < 4; ++r)
        p[nt][r] = exp2f(sv[nt][r] - mnew[r]);
#pragma unroll
    for (int r = 0; r < 4; ++r) {
      float ts = (p[0][r] + p[1][r]) + (p[2][r] + p[3][r]);
#pragma unroll
      for (int off = 1; off < 16; off <<= 1) ts += __shfl_xor(ts, off);
      l_run[r] = l_run[r] * scv[r] + ts;
      m_run[r] = mnew[r];
    }
#pragma unroll
    for (int ct = 0; ct < 4; ++ct) {
      acc[ct][0] *= scv[0]; acc[ct][1] *= scv[1];
      acc[ct][2] *= scv[2]; acc[ct][3] *= scv[3];
    }

    // ---- P -> bf16 into per-wave LDS (transpose for A-fragment) ----
    __bf16* pw = &pbuf[w][0];
#pragma unroll
    for (int nt = 0; nt < 4; ++nt)
#pragma unroll
      for (int r = 0; r < 4; ++r)
        pw[(4 * g + r) * 72 + nt * 16 + qc] = (__bf16)p[nt][r];

    // ---- PV: acc[ct] += P(16q x 64n) * V^T(64n x 16c per tile) ----
#pragma unroll
    for (int s2 = 0; s2 < 2; ++s2) {
      const bf16x8 af = *(const bf16x8*)&pw[qc * 72 + 32 * s2 + 8 * g];
#pragma unroll
      for (int ct = 0; ct < 4; ++ct) {
        const bf16x8 bv = *(const bf16x8*)&vbuf[cur][(ct * 16 + qc) * 72 + 32 * s2 + 8 * g];
        acc[ct] = __builtin_amdgcn_mfma_f32_16x16x32_bf16(af, bv, acc[ct], 0, 0, 0);
      }
    }

    // write prefetched regs -> buf[cur^1]; vmcnt(0) lands here, AFTER compute
    if (it < NITER - 1) {
      if (t < 128) *(int4*)&kbuf[cur ^ 1][kdst] = kreg;
      *(int4*)&vbuf[cur ^ 1][vdst[0]] = vreg0;
      *(int4*)&vbuf[cur ^ 1][vdst[1]] = vreg1;
    }
  }

  if constexpr (NSPLIT == 1) {
    // ---- direct finalize: out += gamma_sa * acc / l ----
    const float gamma = gsa[0];
#pragma unroll
    for (int ct = 0; ct < 4; ++ct) {
      const int c = ct * 16 + qc;
      float* op = out + ((size_t)(b * 64 + c) << 12) + m0 + (w << 4) + 4 * g;
#pragma unroll
      for (int r = 0; r < 4; ++r)
        op[r] += gamma * (acc[ct][r] / l_run[r]);
    }
  } else {
    // ---- store fp32 partials (unnormalized acc, m, l) ----
    float* accB = accP + ((size_t)blk << 12);
#pragma unroll
    for (int ct = 0; ct < 4; ++ct)
#pragma unroll
      for (int r = 0; r < 4; ++r)
        accB[(size_t)((w << 4) + 4 * g + r) * 64 + ct * 16 + qc] = acc[ct][r];
    if (qc == 0) {
#pragma unroll
      for (int r = 0; r < 4; ++r) {
        mP[((size_t)blk << 6) + (w << 4) + 4 * g + r] = m_run[r];
        lP[((size_t)blk << 6) + (w << 4) + 4 * g + r] = l_run[r];
      }
    }
  }
}

// ---------------------------------------------------------------------------
// Kernel 3b: merge the 4 KV-split partials; out += gamma_sa * merged.
// Grid 256 = (b, qt); 256 threads: qrow = t&63, c-chunk = (t>>6)*16.
// ---------------------------------------------------------------------------
__global__ __launch_bounds__(256) void k3b_combine(
    const float* __restrict__ accP, const float* __restrict__ mP,
    const float* __restrict__ lP, const float* __restrict__ gsa,
    float* __restrict__ out)
{
  const int bq = blockIdx.x;              // b*64 + qt
  const int b = bq >> 6;
  const int t = threadIdx.x;
  const int qrow = t & 63;
  const int c0 = (t >> 6) << 4;
  const int blk0 = bq << 2;

  float m[4], l[4];
#pragma unroll
  for (int s = 0; s < 4; ++s) {
    m[s] = mP[((size_t)(blk0 + s) << 6) + qrow];
    l[s] = lP[((size_t)(blk0 + s) << 6) + qrow];
  }
  const float mx = fmaxf(fmaxf(m[0], m[1]), fmaxf(m[2], m[3]));
  float wgt[4]; float L = 0.f;
#pragma unroll
  for (int s = 0; s < 4; ++s) { wgt[s] = exp2f(m[s] - mx); L += l[s] * wgt[s]; }
  const float gamma = gsa[0];
#pragma unroll
  for (int s = 0; s < 4; ++s) wgt[s] = gamma * wgt[s] / L;

  const int qn = ((bq & 63) << 6) + qrow;
#pragma unroll
  for (int cc = 0; cc < 16; cc += 4) {
    f32x4 sum = {0.f, 0.f, 0.f, 0.f};
#pragma unroll
    for (int s = 0; s < 4; ++s)
      sum += wgt[s] * *(const f32x4*)&accP[((size_t)(blk0 + s) << 12) +
                                           (size_t)qrow * 64 + c0 + cc];
#pragma unroll
    for (int j = 0; j < 4; ++j)
      out[((size_t)(b * 64 + c0 + cc + j) << 12) + qn] += sum[j];
  }
}

// ---------------------------------------------------------------------------
extern "C" void kernel_launch(void* const* d_in, const int* in_sizes, int n_in,
                              void* d_out, int out_size, void* d_ws, size_t ws_size,
                              hipStream_t stream)
{
  const float* x   = (const float*)d_in[0];
  const float* wq  = (const float*)d_in[1];
  const float* bq  = (const float*)d_in[2];
  const float* wk  = (const float*)d_in[3];
  const float* bk  = (const float*)d_in[4];
  const float* wv  = (const float*)d_in[5];
  const float* bv  = (const float*)d_in[6];
  const float* gca = (const float*)d_in[7];
  const float* gsa = (const float*)d_in[8];
  float* out = (float*)d_out;

  char* ws = (char*)d_ws;
  float*  att  = (float*)(ws + 65536);                  // 65536 B
  __bf16* qT   = (__bf16*)(ws + 131072);                // 524288 B
  __bf16* kT   = (__bf16*)(ws + 655360);                // 524288 B
  __bf16* vB   = (__bf16*)(ws + 1179648);               // 2097152 B
  float*  accP = (float*)(ws + 3276800);                // 4-split: 16777216 B
  float*  mP   = (float*)(ws + 20054016);               // 262144 B
  float*  lP   = (float*)(ws + 20316160);               // 262144 B -> need 20578304
  // Gp (128 x 64 x 64 fp32 = 2 MB) aliases accP: dead before k3_attn runs.
  float*  Gp   = accP;
  const bool use4 = ws_size >= (size_t)20578304;

  hipLaunchKernelGGL(k1_gram, dim3(128), dim3(256), 0, stream, x, Gp);
  hipLaunchKernelGGL(k1b_softmax, dim3(64), dim3(256), 0, stream, Gp, att);
  hipLaunchKernelGGL(k2_proj, dim3(512), dim3(256), 0, stream,
                     x, att, wq, bq, wk, bk, wv, bv, gca, out, qT, kT, vB);
  if (use4) {
    hipLaunchKernelGGL((k3_attn<4>), dim3(1024), dim3(256), 0, stream,
                       qT, kT, vB, gsa, out, accP, mP, lP);
    hipLaunchKernelGGL(k3b_combine, dim3(256), dim3(256), 0, stream,
                       accP, mP, lP, gsa, out);
  } else {
    hipLaunchKernelGGL((k3_attn<1>), dim3(256), dim3(256), 0, stream,
                       qT, kT, vB, gsa, out, accP, mP, lP);
  }
}